// Round 9
// baseline (278.049 us; speedup 1.0000x reference)
//
#include <hip/hip_runtime.h>
#include <math.h>

#define NN 50000
#define NE 800000
#define DD 128
#define NBUCK 196        // ceil(NN/256) buckets of 256 nodes
#define PTILE 4096       // edges per partition/hist block
#define PBLOCKS 196      // ceil(NE/PTILE)
#define CONVB 6250       // NN*DD/4/256
#define ASLICE 4         // feature slices (32 feats = 64 B each)
#define ABLK 782         // ceil(NN/64) node-blocks per slice
#define LHS 136          // LDS row stride (u16) for fused epilogue

typedef unsigned short u16;
typedef short s8v __attribute__((ext_vector_type(8)));    // 8 bf16 (4 VGPRs)
typedef float f16v __attribute__((ext_vector_type(16)));  // 16 fp32 acc
typedef unsigned u32x4 __attribute__((ext_vector_type(4)));

__device__ __forceinline__ u16 f2bf(float f) {  // RNE fp32->bf16
    unsigned u = __float_as_uint(f);
    return (u16)((u + 0x7FFFu + ((u >> 16) & 1u)) >> 16);
}
__device__ __forceinline__ float bflo(unsigned u) { return __uint_as_float(u << 16); }
__device__ __forceinline__ float bfhi(unsigned u) { return __uint_as_float(u & 0xFFFF0000u); }

// ---- fused prep: x->bf16 conv | 3x weight pack | zero bcnt (R6-proven) ----
__device__ __forceinline__ void pack_one(const float* __restrict__ Wl,
                                         const float* __restrict__ Wr,
                                         bool two, int o, u16* __restrict__ out) {
    int j = o & 7;
    int l = (o >> 3) & 63;
    int cn = o >> 9;
    int n = cn & 3;
    int c = cn >> 2;
    int colj = n * 32 + (l & 31);
    int k = c * 16 + (l >> 5) * 8 + j;
    float v;
    if (two) v = (k < DD) ? Wl[colj * DD + k] : Wr[colj * DD + (k - DD)];
    else     v = Wl[colj * DD + k];
    out[o] = f2bf(v);
}

__global__ __launch_bounds__(256) void prep_kernel(
        const float4* __restrict__ x4, ushort4* __restrict__ hbx,
        const float* __restrict__ Wl, const float* __restrict__ Wr,
        const float* __restrict__ W,
        u16* __restrict__ Bpk0, u16* __restrict__ Bpk1, u16* __restrict__ Bpkf,
        int* __restrict__ bcnt) {
    int bid = blockIdx.x;
    int tid = threadIdx.x;
    if (bid < CONVB) {
        int i = bid * 256 + tid;
        float4 v = x4[i];
        ushort4 o;
        o.x = f2bf(v.x); o.y = f2bf(v.y); o.z = f2bf(v.z); o.w = f2bf(v.w);
        hbx[i] = o;
    } else if (bid < CONVB + 128) {
        pack_one(Wl, Wr, true, (bid - CONVB) * 256 + tid, Bpk0);
    } else if (bid < CONVB + 256) {
        pack_one(Wl + DD * DD, Wr + DD * DD, true, (bid - CONVB - 128) * 256 + tid, Bpk1);
    } else if (bid < CONVB + 320) {
        pack_one(W, W, false, (bid - CONVB - 256) * 256 + tid, Bpkf);
    } else {
        if (tid < NBUCK) bcnt[tid] = 0;
    }
}

// ---- coarse bucket histogram (R6-proven) ----
__global__ __launch_bounds__(256) void bucket_hist(const int* __restrict__ ei,
                                                   int* __restrict__ bcnt) {
    __shared__ int h[NBUCK];
    for (int i = threadIdx.x; i < NBUCK; i += 256) h[i] = 0;
    __syncthreads();
    int e0 = blockIdx.x * PTILE;
#pragma unroll
    for (int i = 0; i < 16; i++) {
        int e = e0 + i * 256 + threadIdx.x;
        if (e < NE) atomicAdd(&h[ei[NE + e] >> 8], 1);
    }
    __syncthreads();
    for (int i = threadIdx.x; i < NBUCK; i += 256)
        if (h[i]) atomicAdd(&bcnt[i], h[i]);
}

// ---- scan bucket counts -> bases + cursors ----
__global__ __launch_bounds__(256) void bucket_scan(const int* __restrict__ bcnt,
                                                   int* __restrict__ bbase,
                                                   int* __restrict__ bcur,
                                                   int* __restrict__ rowptr) {
    __shared__ int s[256];
    int t = threadIdx.x;
    int v = (t < NBUCK) ? bcnt[t] : 0;
    s[t] = v;
    __syncthreads();
    for (int o = 1; o < 256; o <<= 1) {
        int u = (t >= o) ? s[t - o] : 0;
        __syncthreads();
        s[t] += u;
        __syncthreads();
    }
    int ex = s[t] - v;
    if (t < NBUCK) { bbase[t] = ex; bcur[t] = ex; }
    if (t == 0) rowptr[NN] = NE;
}

// ---- partition edges into bucket-contiguous packed array (R6-proven) ----
__global__ __launch_bounds__(256) void bucket_partition(const int* __restrict__ ei,
                                                        int* __restrict__ bcur,
                                                        unsigned* __restrict__ packed) {
    __shared__ int h[NBUCK];
    __shared__ int base[NBUCK];
    int t = threadIdx.x;
    for (int i = t; i < NBUCK; i += 256) h[i] = 0;
    __syncthreads();
    int e0 = blockIdx.x * PTILE;
    int dsts[16], srcs[16];
#pragma unroll
    for (int i = 0; i < 16; i++) {
        int e = e0 + i * 256 + t;
        if (e < NE) {
            dsts[i] = ei[NE + e];
            srcs[i] = ei[e];
            atomicAdd(&h[dsts[i] >> 8], 1);
        } else dsts[i] = -1;
    }
    __syncthreads();
    for (int i = t; i < NBUCK; i += 256) {
        int c = h[i];
        base[i] = c ? atomicAdd(&bcur[i], c) : 0;
    }
    __syncthreads();
    for (int i = t; i < NBUCK; i += 256) h[i] = 0;  // reuse as local cursor
    __syncthreads();
#pragma unroll
    for (int i = 0; i < 16; i++) {
        if (dsts[i] >= 0) {
            int bk = dsts[i] >> 8;
            int r = atomicAdd(&h[bk], 1);
            packed[base[bk] + r] = (unsigned)srcs[i] | ((unsigned)(dsts[i] & 255) << 16);
        }
    }
}

// ---- per-bucket counting sort -> rowptr + col (R6-proven, no perm) ----
__global__ __launch_bounds__(256) void bucket_csr(const unsigned* __restrict__ packed,
                                                  const int* __restrict__ bcnt,
                                                  const int* __restrict__ bbase,
                                                  int* __restrict__ rowptr,
                                                  int* __restrict__ col) {
    __shared__ int deg[256];
    __shared__ int off[256];
    int bk = blockIdx.x;
    int cnt = bcnt[bk], base = bbase[bk];
    int t = threadIdx.x;
    deg[t] = 0;
    __syncthreads();
    for (int i = t; i < cnt; i += 256) atomicAdd(&deg[packed[base + i] >> 16], 1);
    __syncthreads();
    int v = deg[t];
    off[t] = v;
    __syncthreads();
    for (int o = 1; o < 256; o <<= 1) {
        int u = (t >= o) ? off[t - o] : 0;
        __syncthreads();
        off[t] += u;
        __syncthreads();
    }
    int ex = off[t] - v;
    int node = (bk << 8) + t;
    if (node < NN) rowptr[node] = base + ex;
    deg[t] = ex;  // reuse as cursor
    __syncthreads();
    for (int i = t; i < cnt; i += 256) {
        unsigned p = packed[base + i];
        int dl = p >> 16;
        int r = atomicAdd(&deg[dl], 1);
        col[base + r] = (int)(p & 0xFFFFu);
    }
}

// ---- sliced segmented max: 4 slices x 32 feats; NT store agg, NT load col ----
// slice working set = 3.2 MB (fits 4 MB XCD L2); NT keeps write/col streams out of L2.
__device__ __forceinline__ void vmax8(float* m, u32x4 v) {
    m[0] = fmaxf(m[0], bflo(v.x)); m[1] = fmaxf(m[1], bfhi(v.x));
    m[2] = fmaxf(m[2], bflo(v.y)); m[3] = fmaxf(m[3], bfhi(v.y));
    m[4] = fmaxf(m[4], bflo(v.z)); m[5] = fmaxf(m[5], bfhi(v.z));
    m[6] = fmaxf(m[6], bflo(v.w)); m[7] = fmaxf(m[7], bfhi(v.w));
}

__global__ __launch_bounds__(256) void agg_kernel_bf(const u32x4* __restrict__ xb4,
                                                     const int* __restrict__ row_ptr,
                                                     const int* __restrict__ col,
                                                     u32x4* __restrict__ aggb4) {
    int bid = blockIdx.x;
    int slice = bid / ABLK;          // slice-major: co-resident blocks share a slice
    int blk = bid - slice * ABLK;
    int node = blk * 64 + (threadIdx.x >> 2);
    if (node >= NN) return;
    int j = (threadIdx.x & 3) + slice * 4;   // u32x4 index within the 16-u32x4 row
    int s0 = row_ptr[node], s1 = row_ptr[node + 1];
    u32x4* outp = aggb4 + (size_t)node * 16 + j;
    if (s0 == s1) {
        u32x4 z = (u32x4)(0u);
        __builtin_nontemporal_store(z, outp);
        return;
    }
    float m0[8], m1[8], m2[8], m3[8];
#pragma unroll
    for (int q = 0; q < 8; q++) { m0[q] = m1[q] = m2[q] = m3[q] = -INFINITY; }
    int i = s0;
    for (; i + 8 <= s1; i += 8) {
        int c0 = __builtin_nontemporal_load(&col[i]);
        int c1 = __builtin_nontemporal_load(&col[i + 1]);
        int c2 = __builtin_nontemporal_load(&col[i + 2]);
        int c3 = __builtin_nontemporal_load(&col[i + 3]);
        int c4 = __builtin_nontemporal_load(&col[i + 4]);
        int c5 = __builtin_nontemporal_load(&col[i + 5]);
        int c6 = __builtin_nontemporal_load(&col[i + 6]);
        int c7 = __builtin_nontemporal_load(&col[i + 7]);
        u32x4 v0 = xb4[(size_t)c0 * 16 + j];
        u32x4 v1 = xb4[(size_t)c1 * 16 + j];
        u32x4 v2 = xb4[(size_t)c2 * 16 + j];
        u32x4 v3 = xb4[(size_t)c3 * 16 + j];
        u32x4 v4 = xb4[(size_t)c4 * 16 + j];
        u32x4 v5 = xb4[(size_t)c5 * 16 + j];
        u32x4 v6 = xb4[(size_t)c6 * 16 + j];
        u32x4 v7 = xb4[(size_t)c7 * 16 + j];
        vmax8(m0, v0); vmax8(m1, v1); vmax8(m2, v2); vmax8(m3, v3);
        vmax8(m0, v4); vmax8(m1, v5); vmax8(m2, v6); vmax8(m3, v7);
    }
    for (; i + 4 <= s1; i += 4) {
        int c0 = __builtin_nontemporal_load(&col[i]);
        int c1 = __builtin_nontemporal_load(&col[i + 1]);
        int c2 = __builtin_nontemporal_load(&col[i + 2]);
        int c3 = __builtin_nontemporal_load(&col[i + 3]);
        u32x4 v0 = xb4[(size_t)c0 * 16 + j];
        u32x4 v1 = xb4[(size_t)c1 * 16 + j];
        u32x4 v2 = xb4[(size_t)c2 * 16 + j];
        u32x4 v3 = xb4[(size_t)c3 * 16 + j];
        vmax8(m0, v0); vmax8(m1, v1); vmax8(m2, v2); vmax8(m3, v3);
    }
    for (; i < s1; i++) {
        int c0 = __builtin_nontemporal_load(&col[i]);
        u32x4 v = xb4[(size_t)c0 * 16 + j];
        vmax8(m0, v);
    }
#pragma unroll
    for (int q = 0; q < 8; q++) m0[q] = fmaxf(fmaxf(m0[q], m1[q]), fmaxf(m2[q], m3[q]));
    u32x4 o;  // values are exact bf16 -> pack by truncation
    o.x = (__float_as_uint(m0[0]) >> 16) | (__float_as_uint(m0[1]) & 0xFFFF0000u);
    o.y = (__float_as_uint(m0[2]) >> 16) | (__float_as_uint(m0[3]) & 0xFFFF0000u);
    o.z = (__float_as_uint(m0[4]) >> 16) | (__float_as_uint(m0[5]) & 0xFFFF0000u);
    o.w = (__float_as_uint(m0[6]) >> 16) | (__float_as_uint(m0[7]) & 0xFFFF0000u);
    __builtin_nontemporal_store(o, outp);
}

// ---------------- MFMA GEMM layer 0 (no LDS; B-fragments from L2) ----------------
__global__ __launch_bounds__(256) void mfma_gemm0(const u16* __restrict__ srcA,
                                                  const u16* __restrict__ srcB,
                                                  const u16* __restrict__ Bpk,
                                                  const float* __restrict__ bias,
                                                  u16* __restrict__ outb) {
    int tid = threadIdx.x;
    int wt = tid >> 6;
    int lane = tid & 63;
    int row0 = blockIdx.x * 128 + wt * 32;
    int rload = row0 + (lane & 31);
    if (rload > NN - 1) rload = NN - 1;
    int koff = (lane >> 5) * 8;
    const s8v* Bv = (const s8v*)Bpk;

    f16v acc[4];
#pragma unroll
    for (int n = 0; n < 4; n++) acc[n] = (f16v)(0.0f);

#pragma unroll
    for (int c = 0; c < 16; c++) {
        const u16* s = (c >= 8) ? srcB : srcA;
        int kk = (c >= 8) ? (c - 8) * 16 : c * 16;
        s8v a = *(const s8v*)(s + (size_t)rload * DD + kk + koff);
#pragma unroll
        for (int n = 0; n < 4; n++) {
            s8v b = Bv[(c * 4 + n) * 64 + lane];
            acc[n] = __builtin_amdgcn_mfma_f32_32x32x16_bf16(a, b, acc[n], 0, 0, 0);
        }
    }

    int rowadd = 4 * (lane >> 5);
#pragma unroll
    for (int n = 0; n < 4; n++) {
        int colj = n * 32 + (lane & 31);
        float bj = bias[colj];
#pragma unroll
        for (int r = 0; r < 16; r++) {
            int row = row0 + (r & 3) + 8 * (r >> 2) + rowadd;
            if (row < NN) outb[(size_t)row * DD + colj] = f2bf(fmaxf(acc[n][r] + bj, 0.0f));
        }
    }
}

// ------- MFMA GEMM layer 1 fused with final linear (R8-proven) -------
__global__ __launch_bounds__(256) void mfma_gemm1_final(const u16* __restrict__ srcA,
                                                        const u16* __restrict__ srcB,
                                                        const u16* __restrict__ Bpk1,
                                                        const float* __restrict__ bias1,
                                                        const u16* __restrict__ Bpkf,
                                                        const float* __restrict__ bias2,
                                                        float* __restrict__ out) {
    __shared__ u16 lh[128 * LHS];
    int tid = threadIdx.x;
    int wt = tid >> 6;
    int lane = tid & 63;
    int row0 = blockIdx.x * 128 + wt * 32;
    int rload = row0 + (lane & 31);
    if (rload > NN - 1) rload = NN - 1;
    int koff = (lane >> 5) * 8;
    const s8v* Bv1 = (const s8v*)Bpk1;
    const s8v* Bvf = (const s8v*)Bpkf;

    f16v acc[4];
#pragma unroll
    for (int n = 0; n < 4; n++) acc[n] = (f16v)(0.0f);

#pragma unroll
    for (int c = 0; c < 16; c++) {
        const u16* s = (c >= 8) ? srcB : srcA;
        int kk = (c >= 8) ? (c - 8) * 16 : c * 16;
        s8v a = *(const s8v*)(s + (size_t)rload * DD + kk + koff);
#pragma unroll
        for (int n = 0; n < 4; n++) {
            s8v b = Bv1[(c * 4 + n) * 64 + lane];
            acc[n] = __builtin_amdgcn_mfma_f32_32x32x16_bf16(a, b, acc[n], 0, 0, 0);
        }
    }

    // epilogue 1: h1 = relu(acc + b1) -> LDS (bf16), C-layout -> row-major
    int rowadd = 4 * (lane >> 5);
#pragma unroll
    for (int n = 0; n < 4; n++) {
        int colj = n * 32 + (lane & 31);
        float bj = bias1[colj];
#pragma unroll
        for (int r = 0; r < 16; r++) {
            int rl = (r & 3) + 8 * (r >> 2) + rowadd;
            lh[(wt * 32 + rl) * LHS + colj] = f2bf(fmaxf(acc[n][r] + bj, 0.0f));
        }
    }
    __syncthreads();

    // final GEMM: A from LDS (wave's own 32 rows), B = Bpkf, K=128
    f16v acc2[4];
#pragma unroll
    for (int n = 0; n < 4; n++) acc2[n] = (f16v)(0.0f);
    int m = lane & 31;
#pragma unroll
    for (int c = 0; c < 8; c++) {
        s8v a = *(const s8v*)&lh[(wt * 32 + m) * LHS + c * 16 + koff];
#pragma unroll
        for (int n = 0; n < 4; n++) {
            s8v b = Bvf[(c * 4 + n) * 64 + lane];
            acc2[n] = __builtin_amdgcn_mfma_f32_32x32x16_bf16(a, b, acc2[n], 0, 0, 0);
        }
    }

#pragma unroll
    for (int n = 0; n < 4; n++) {
        int colj = n * 32 + (lane & 31);
        float bj = bias2[colj];
#pragma unroll
        for (int r = 0; r < 16; r++) {
            int row = row0 + (r & 3) + 8 * (r >> 2) + rowadd;
            if (row < NN) out[(size_t)row * DD + colj] = acc2[n][r] + bj;
        }
    }
}

extern "C" void kernel_launch(void* const* d_in, const int* in_sizes, int n_in,
                              void* d_out, int out_size, void* d_ws, size_t ws_size,
                              hipStream_t stream) {
    const float* x  = (const float*)d_in[0];
    const int*   ei = (const int*)d_in[1];
    const float* Wl = (const float*)d_in[2];
    const float* bl = (const float*)d_in[3];
    const float* Wr = (const float*)d_in[4];
    const float* W  = (const float*)d_in[5];
    const float* b  = (const float*)d_in[6];
    float* out = (float*)d_out;

    // ws layout (16B-aligned chunks)
    u16* aggb = (u16*)d_ws;                         // NN*DD bf16
    u16* hbx  = aggb + (size_t)NN * DD;             // NN*DD  (bf16 of x)
    u16* h1   = hbx + (size_t)NN * DD;              // NN*DD  (layer-0 output)
    u16* Bpk0 = h1 + (size_t)NN * DD;               // 32768
    u16* Bpk1 = Bpk0 + 32768;                       // 32768
    u16* Bpkf = Bpk1 + 32768;                       // 16384
    unsigned* packed = (unsigned*)(Bpkf + 16384);   // NE u32
    int* col    = (int*)(packed + NE);              // NE
    int* rowptr = col + NE;                         // NN+1
    int* bcnt   = rowptr + NN + 1;                  // NBUCK
    int* bbase  = bcnt + NBUCK;                     // NBUCK
    int* bcur   = bbase + NBUCK;                    // NBUCK

    dim3 blk(256);
    int gemmBlocks = (NN + 127) / 128;               // 391
    int aggBlocks  = ASLICE * ABLK;                  // 3128
    int prepBlocks = CONVB + 320 + 1;                // conv + packs + zero

    // fused prep (conv + weight packs + bcnt zero)
    prep_kernel<<<prepBlocks, blk, 0, stream>>>(
        (const float4*)x, (ushort4*)hbx, Wl, Wr, W, Bpk0, Bpk1, Bpkf, bcnt);

    // CSR build (R6-proven chain)
    bucket_hist<<<PBLOCKS, blk, 0, stream>>>(ei, bcnt);
    bucket_scan<<<1, blk, 0, stream>>>(bcnt, bbase, bcur, rowptr);
    bucket_partition<<<PBLOCKS, blk, 0, stream>>>(ei, bcur, packed);
    bucket_csr<<<NBUCK, blk, 0, stream>>>(packed, bcnt, bbase, rowptr, col);

    // Layer 0
    agg_kernel_bf<<<aggBlocks, blk, 0, stream>>>((const u32x4*)hbx, rowptr, col, (u32x4*)aggb);
    mfma_gemm0<<<gemmBlocks, blk, 0, stream>>>(aggb, hbx, Bpk0, bl, h1);

    // Layer 1 + final linear (fused)
    agg_kernel_bf<<<aggBlocks, blk, 0, stream>>>((const u32x4*)h1, rowptr, col, (u32x4*)aggb);
    mfma_gemm1_final<<<gemmBlocks, blk, 0, stream>>>(aggb, h1, Bpk1, bl + DD, Bpkf, b, out);
}

// Round 10
// 244.063 us; speedup vs baseline: 1.1393x; 1.1393x over previous
//
#include <hip/hip_runtime.h>
#include <math.h>

#define NN 50000
#define NE 800000
#define DD 128
#define NBUCK 196        // ceil(NN/256) buckets of 256 nodes
#define PTILE 4096       // edges per partition/hist block
#define PBLOCKS 196      // ceil(NE/PTILE)
#define CONVB 6250       // NN*DD/4/256
#define LHS 136          // LDS row stride (u16) for fused epilogue

typedef unsigned short u16;
typedef short s8v __attribute__((ext_vector_type(8)));    // 8 bf16 (4 VGPRs)
typedef float f16v __attribute__((ext_vector_type(16)));  // 16 fp32 acc

__device__ __forceinline__ u16 f2bf(float f) {  // RNE fp32->bf16
    unsigned u = __float_as_uint(f);
    return (u16)((u + 0x7FFFu + ((u >> 16) & 1u)) >> 16);
}
__device__ __forceinline__ float bflo(unsigned u) { return __uint_as_float(u << 16); }
__device__ __forceinline__ float bfhi(unsigned u) { return __uint_as_float(u & 0xFFFF0000u); }

// ---- fused prep: x->bf16 conv | 3x weight pack | zero bcnt (R6-proven) ----
// pack order: out[((c*4+n)*64+l)*8+j] = Wcat[col=n*32+(l&31)][k=c*16+(l>>5)*8+j]
__device__ __forceinline__ void pack_one(const float* __restrict__ Wl,
                                         const float* __restrict__ Wr,
                                         bool two, int o, u16* __restrict__ out) {
    int j = o & 7;
    int l = (o >> 3) & 63;
    int cn = o >> 9;
    int n = cn & 3;
    int c = cn >> 2;
    int colj = n * 32 + (l & 31);
    int k = c * 16 + (l >> 5) * 8 + j;
    float v;
    if (two) v = (k < DD) ? Wl[colj * DD + k] : Wr[colj * DD + (k - DD)];
    else     v = Wl[colj * DD + k];
    out[o] = f2bf(v);
}

__global__ __launch_bounds__(256) void prep_kernel(
        const float4* __restrict__ x4, ushort4* __restrict__ hbx,
        const float* __restrict__ Wl, const float* __restrict__ Wr,
        const float* __restrict__ W,
        u16* __restrict__ Bpk0, u16* __restrict__ Bpk1, u16* __restrict__ Bpkf,
        int* __restrict__ bcnt) {
    int bid = blockIdx.x;
    int tid = threadIdx.x;
    if (bid < CONVB) {
        int i = bid * 256 + tid;
        float4 v = x4[i];
        ushort4 o;
        o.x = f2bf(v.x); o.y = f2bf(v.y); o.z = f2bf(v.z); o.w = f2bf(v.w);
        hbx[i] = o;
    } else if (bid < CONVB + 128) {
        pack_one(Wl, Wr, true, (bid - CONVB) * 256 + tid, Bpk0);
    } else if (bid < CONVB + 256) {
        pack_one(Wl + DD * DD, Wr + DD * DD, true, (bid - CONVB - 128) * 256 + tid, Bpk1);
    } else if (bid < CONVB + 320) {
        pack_one(W, W, false, (bid - CONVB - 256) * 256 + tid, Bpkf);
    } else {
        if (tid < NBUCK) bcnt[tid] = 0;
    }
}

// ---- coarse bucket histogram (R6-proven) ----
__global__ __launch_bounds__(256) void bucket_hist(const int* __restrict__ ei,
                                                   int* __restrict__ bcnt) {
    __shared__ int h[NBUCK];
    for (int i = threadIdx.x; i < NBUCK; i += 256) h[i] = 0;
    __syncthreads();
    int e0 = blockIdx.x * PTILE;
#pragma unroll
    for (int i = 0; i < 16; i++) {
        int e = e0 + i * 256 + threadIdx.x;
        if (e < NE) atomicAdd(&h[ei[NE + e] >> 8], 1);
    }
    __syncthreads();
    for (int i = threadIdx.x; i < NBUCK; i += 256)
        if (h[i]) atomicAdd(&bcnt[i], h[i]);
}

// ---- scan bucket counts -> bases + cursors ----
__global__ __launch_bounds__(256) void bucket_scan(const int* __restrict__ bcnt,
                                                   int* __restrict__ bbase,
                                                   int* __restrict__ bcur,
                                                   int* __restrict__ rowptr) {
    __shared__ int s[256];
    int t = threadIdx.x;
    int v = (t < NBUCK) ? bcnt[t] : 0;
    s[t] = v;
    __syncthreads();
    for (int o = 1; o < 256; o <<= 1) {
        int u = (t >= o) ? s[t - o] : 0;
        __syncthreads();
        s[t] += u;
        __syncthreads();
    }
    int ex = s[t] - v;
    if (t < NBUCK) { bbase[t] = ex; bcur[t] = ex; }
    if (t == 0) rowptr[NN] = NE;
}

// ---- partition edges into bucket-contiguous packed array (R6-proven) ----
__global__ __launch_bounds__(256) void bucket_partition(const int* __restrict__ ei,
                                                        int* __restrict__ bcur,
                                                        unsigned* __restrict__ packed) {
    __shared__ int h[NBUCK];
    __shared__ int base[NBUCK];
    int t = threadIdx.x;
    for (int i = t; i < NBUCK; i += 256) h[i] = 0;
    __syncthreads();
    int e0 = blockIdx.x * PTILE;
    int dsts[16], srcs[16];
#pragma unroll
    for (int i = 0; i < 16; i++) {
        int e = e0 + i * 256 + t;
        if (e < NE) {
            dsts[i] = ei[NE + e];
            srcs[i] = ei[e];
            atomicAdd(&h[dsts[i] >> 8], 1);
        } else dsts[i] = -1;
    }
    __syncthreads();
    for (int i = t; i < NBUCK; i += 256) {
        int c = h[i];
        base[i] = c ? atomicAdd(&bcur[i], c) : 0;
    }
    __syncthreads();
    for (int i = t; i < NBUCK; i += 256) h[i] = 0;  // reuse as local cursor
    __syncthreads();
#pragma unroll
    for (int i = 0; i < 16; i++) {
        if (dsts[i] >= 0) {
            int bk = dsts[i] >> 8;
            int r = atomicAdd(&h[bk], 1);
            packed[base[bk] + r] = (unsigned)srcs[i] | ((unsigned)(dsts[i] & 255) << 16);
        }
    }
}

// ---- per-bucket counting sort -> rowptr + col (R6-proven) ----
__global__ __launch_bounds__(256) void bucket_csr(const unsigned* __restrict__ packed,
                                                  const int* __restrict__ bcnt,
                                                  const int* __restrict__ bbase,
                                                  int* __restrict__ rowptr,
                                                  int* __restrict__ col) {
    __shared__ int deg[256];
    __shared__ int off[256];
    int bk = blockIdx.x;
    int cnt = bcnt[bk], base = bbase[bk];
    int t = threadIdx.x;
    deg[t] = 0;
    __syncthreads();
    for (int i = t; i < cnt; i += 256) atomicAdd(&deg[packed[base + i] >> 16], 1);
    __syncthreads();
    int v = deg[t];
    off[t] = v;
    __syncthreads();
    for (int o = 1; o < 256; o <<= 1) {
        int u = (t >= o) ? off[t - o] : 0;
        __syncthreads();
        off[t] += u;
        __syncthreads();
    }
    int ex = off[t] - v;
    int node = (bk << 8) + t;
    if (node < NN) rowptr[node] = base + ex;
    deg[t] = ex;  // reuse as cursor
    __syncthreads();
    for (int i = t; i < cnt; i += 256) {
        unsigned p = packed[base + i];
        int dl = p >> 16;
        int r = atomicAdd(&deg[dl], 1);
        col[base + r] = (int)(p & 0xFFFFu);
    }
}

// ---- segmented max on bf16 (CSR), 16 lanes/node, 16B/lane, unroll-8 (R6-proven) ----
__device__ __forceinline__ void vmax8(float* m, uint4 v) {
    m[0] = fmaxf(m[0], bflo(v.x)); m[1] = fmaxf(m[1], bfhi(v.x));
    m[2] = fmaxf(m[2], bflo(v.y)); m[3] = fmaxf(m[3], bfhi(v.y));
    m[4] = fmaxf(m[4], bflo(v.z)); m[5] = fmaxf(m[5], bfhi(v.z));
    m[6] = fmaxf(m[6], bflo(v.w)); m[7] = fmaxf(m[7], bfhi(v.w));
}

__global__ __launch_bounds__(256) void agg_kernel_bf(const uint4* __restrict__ xb4,
                                                     const int* __restrict__ row_ptr,
                                                     const int* __restrict__ col,
                                                     uint4* __restrict__ aggb4) {
    int node = blockIdx.x * 16 + (threadIdx.x >> 4);
    if (node >= NN) return;
    int j = threadIdx.x & 15;
    int s0 = row_ptr[node], s1 = row_ptr[node + 1];
    if (s0 == s1) {
        aggb4[(size_t)node * 16 + j] = make_uint4(0, 0, 0, 0);
        return;
    }
    float m0[8], m1[8], m2[8], m3[8];
#pragma unroll
    for (int q = 0; q < 8; q++) { m0[q] = m1[q] = m2[q] = m3[q] = -INFINITY; }
    int i = s0;
    for (; i + 8 <= s1; i += 8) {
        int c0 = col[i],     c1 = col[i + 1], c2 = col[i + 2], c3 = col[i + 3];
        int c4 = col[i + 4], c5 = col[i + 5], c6 = col[i + 6], c7 = col[i + 7];
        uint4 v0 = xb4[(size_t)c0 * 16 + j];
        uint4 v1 = xb4[(size_t)c1 * 16 + j];
        uint4 v2 = xb4[(size_t)c2 * 16 + j];
        uint4 v3 = xb4[(size_t)c3 * 16 + j];
        uint4 v4 = xb4[(size_t)c4 * 16 + j];
        uint4 v5 = xb4[(size_t)c5 * 16 + j];
        uint4 v6 = xb4[(size_t)c6 * 16 + j];
        uint4 v7 = xb4[(size_t)c7 * 16 + j];
        vmax8(m0, v0); vmax8(m1, v1); vmax8(m2, v2); vmax8(m3, v3);
        vmax8(m0, v4); vmax8(m1, v5); vmax8(m2, v6); vmax8(m3, v7);
    }
    for (; i + 4 <= s1; i += 4) {
        int c0 = col[i], c1 = col[i + 1], c2 = col[i + 2], c3 = col[i + 3];
        uint4 v0 = xb4[(size_t)c0 * 16 + j];
        uint4 v1 = xb4[(size_t)c1 * 16 + j];
        uint4 v2 = xb4[(size_t)c2 * 16 + j];
        uint4 v3 = xb4[(size_t)c3 * 16 + j];
        vmax8(m0, v0); vmax8(m1, v1); vmax8(m2, v2); vmax8(m3, v3);
    }
    for (; i < s1; i++) {
        uint4 v = xb4[(size_t)col[i] * 16 + j];
        vmax8(m0, v);
    }
#pragma unroll
    for (int q = 0; q < 8; q++) m0[q] = fmaxf(fmaxf(m0[q], m1[q]), fmaxf(m2[q], m3[q]));
    uint4 o;  // values are exact bf16 -> pack by truncation
    o.x = (__float_as_uint(m0[0]) >> 16) | (__float_as_uint(m0[1]) & 0xFFFF0000u);
    o.y = (__float_as_uint(m0[2]) >> 16) | (__float_as_uint(m0[3]) & 0xFFFF0000u);
    o.z = (__float_as_uint(m0[4]) >> 16) | (__float_as_uint(m0[5]) & 0xFFFF0000u);
    o.w = (__float_as_uint(m0[6]) >> 16) | (__float_as_uint(m0[7]) & 0xFFFF0000u);
    aggb4[(size_t)node * 16 + j] = o;
}

// ---------------- MFMA GEMM layer 0 (no LDS; B-fragments from L2; R6-proven) ----------------
__global__ __launch_bounds__(256) void mfma_gemm0(const u16* __restrict__ srcA,
                                                  const u16* __restrict__ srcB,
                                                  const u16* __restrict__ Bpk,
                                                  const float* __restrict__ bias,
                                                  u16* __restrict__ outb) {
    int tid = threadIdx.x;
    int wt = tid >> 6;
    int lane = tid & 63;
    int row0 = blockIdx.x * 128 + wt * 32;
    int rload = row0 + (lane & 31);
    if (rload > NN - 1) rload = NN - 1;  // clamp OOB loads
    int koff = (lane >> 5) * 8;
    const s8v* Bv = (const s8v*)Bpk;

    f16v acc[4];
#pragma unroll
    for (int n = 0; n < 4; n++) acc[n] = (f16v)(0.0f);

#pragma unroll
    for (int c = 0; c < 16; c++) {
        const u16* s = (c >= 8) ? srcB : srcA;
        int kk = (c >= 8) ? (c - 8) * 16 : c * 16;
        s8v a = *(const s8v*)(s + (size_t)rload * DD + kk + koff);
#pragma unroll
        for (int n = 0; n < 4; n++) {
            s8v b = Bv[(c * 4 + n) * 64 + lane];
            acc[n] = __builtin_amdgcn_mfma_f32_32x32x16_bf16(a, b, acc[n], 0, 0, 0);
        }
    }

    // epilogue: C/D layout col=lane&31, row=(reg&3)+8*(reg>>2)+4*(lane>>5)
    int rowadd = 4 * (lane >> 5);
#pragma unroll
    for (int n = 0; n < 4; n++) {
        int colj = n * 32 + (lane & 31);
        float bj = bias[colj];
#pragma unroll
        for (int r = 0; r < 16; r++) {
            int row = row0 + (r & 3) + 8 * (r >> 2) + rowadd;
            if (row < NN) outb[(size_t)row * DD + colj] = f2bf(fmaxf(acc[n][r] + bj, 0.0f));
        }
    }
}

// ------- MFMA GEMM layer 1 fused with final linear (R8-proven) -------
__global__ __launch_bounds__(256) void mfma_gemm1_final(const u16* __restrict__ srcA,
                                                        const u16* __restrict__ srcB,
                                                        const u16* __restrict__ Bpk1,
                                                        const float* __restrict__ bias1,
                                                        const u16* __restrict__ Bpkf,
                                                        const float* __restrict__ bias2,
                                                        float* __restrict__ out) {
    __shared__ u16 lh[128 * LHS];
    int tid = threadIdx.x;
    int wt = tid >> 6;
    int lane = tid & 63;
    int row0 = blockIdx.x * 128 + wt * 32;
    int rload = row0 + (lane & 31);
    if (rload > NN - 1) rload = NN - 1;
    int koff = (lane >> 5) * 8;
    const s8v* Bv1 = (const s8v*)Bpk1;
    const s8v* Bvf = (const s8v*)Bpkf;

    f16v acc[4];
#pragma unroll
    for (int n = 0; n < 4; n++) acc[n] = (f16v)(0.0f);

#pragma unroll
    for (int c = 0; c < 16; c++) {
        const u16* s = (c >= 8) ? srcB : srcA;
        int kk = (c >= 8) ? (c - 8) * 16 : c * 16;
        s8v a = *(const s8v*)(s + (size_t)rload * DD + kk + koff);
#pragma unroll
        for (int n = 0; n < 4; n++) {
            s8v b = Bv1[(c * 4 + n) * 64 + lane];
            acc[n] = __builtin_amdgcn_mfma_f32_32x32x16_bf16(a, b, acc[n], 0, 0, 0);
        }
    }

    // epilogue 1: h1 = relu(acc + b1) -> LDS (bf16), C-layout -> row-major
    int rowadd = 4 * (lane >> 5);
#pragma unroll
    for (int n = 0; n < 4; n++) {
        int colj = n * 32 + (lane & 31);
        float bj = bias1[colj];
#pragma unroll
        for (int r = 0; r < 16; r++) {
            int rl = (r & 3) + 8 * (r >> 2) + rowadd;
            lh[(wt * 32 + rl) * LHS + colj] = f2bf(fmaxf(acc[n][r] + bj, 0.0f));
        }
    }
    __syncthreads();

    // final GEMM: A from LDS (wave's own 32 rows), B = Bpkf, K=128
    f16v acc2[4];
#pragma unroll
    for (int n = 0; n < 4; n++) acc2[n] = (f16v)(0.0f);
    int m = lane & 31;
#pragma unroll
    for (int c = 0; c < 8; c++) {
        s8v a = *(const s8v*)&lh[(wt * 32 + m) * LHS + c * 16 + koff];
#pragma unroll
        for (int n = 0; n < 4; n++) {
            s8v b = Bvf[(c * 4 + n) * 64 + lane];
            acc2[n] = __builtin_amdgcn_mfma_f32_32x32x16_bf16(a, b, acc2[n], 0, 0, 0);
        }
    }

#pragma unroll
    for (int n = 0; n < 4; n++) {
        int colj = n * 32 + (lane & 31);
        float bj = bias2[colj];
#pragma unroll
        for (int r = 0; r < 16; r++) {
            int row = row0 + (r & 3) + 8 * (r >> 2) + rowadd;
            if (row < NN) out[(size_t)row * DD + colj] = acc2[n][r] + bj;
        }
    }
}

extern "C" void kernel_launch(void* const* d_in, const int* in_sizes, int n_in,
                              void* d_out, int out_size, void* d_ws, size_t ws_size,
                              hipStream_t stream) {
    const float* x  = (const float*)d_in[0];
    const int*   ei = (const int*)d_in[1];
    const float* Wl = (const float*)d_in[2];
    const float* bl = (const float*)d_in[3];
    const float* Wr = (const float*)d_in[4];
    const float* W  = (const float*)d_in[5];
    const float* b  = (const float*)d_in[6];
    float* out = (float*)d_out;

    // ws layout (16B-aligned chunks)
    u16* aggb = (u16*)d_ws;                         // NN*DD bf16
    u16* hbx  = aggb + (size_t)NN * DD;             // NN*DD  (bf16 of x)
    u16* h1   = hbx + (size_t)NN * DD;              // NN*DD  (layer-0 output)
    u16* Bpk0 = h1 + (size_t)NN * DD;               // 32768
    u16* Bpk1 = Bpk0 + 32768;                       // 32768
    u16* Bpkf = Bpk1 + 32768;                       // 16384
    unsigned* packed = (unsigned*)(Bpkf + 16384);   // NE u32
    int* col    = (int*)(packed + NE);              // NE
    int* rowptr = col + NE;                         // NN+1
    int* bcnt   = rowptr + NN + 1;                  // NBUCK
    int* bbase  = bcnt + NBUCK;                     // NBUCK
    int* bcur   = bbase + NBUCK;                    // NBUCK

    dim3 blk(256);
    int gemmBlocks = (NN + 127) / 128;               // 391
    int aggBlocks  = (NN + 15) / 16;                 // 3125
    int prepBlocks = CONVB + 320 + 1;                // conv + packs + zero

    // fused prep (conv + weight packs + bcnt zero)
    prep_kernel<<<prepBlocks, blk, 0, stream>>>(
        (const float4*)x, (ushort4*)hbx, Wl, Wr, W, Bpk0, Bpk1, Bpkf, bcnt);

    // CSR build (R6-proven chain)
    bucket_hist<<<PBLOCKS, blk, 0, stream>>>(ei, bcnt);
    bucket_scan<<<1, blk, 0, stream>>>(bcnt, bbase, bcur, rowptr);
    bucket_partition<<<PBLOCKS, blk, 0, stream>>>(ei, bcur, packed);
    bucket_csr<<<NBUCK, blk, 0, stream>>>(packed, bcnt, bbase, rowptr, col);

    // Layer 0
    agg_kernel_bf<<<aggBlocks, blk, 0, stream>>>((const uint4*)hbx, rowptr, col, (uint4*)aggb);
    mfma_gemm0<<<gemmBlocks, blk, 0, stream>>>(aggb, hbx, Bpk0, bl, h1);

    // Layer 1 + final linear (fused)
    agg_kernel_bf<<<aggBlocks, blk, 0, stream>>>((const uint4*)h1, rowptr, col, (uint4*)aggb);
    mfma_gemm1_final<<<gemmBlocks, blk, 0, stream>>>(aggb, h1, Bpk1, bl + DD, Bpkf, b, out);
}